// Round 9
// baseline (172.623 us; speedup 1.0000x reference)
//
#include <hip/hip_runtime.h>
#include <hip/hip_bf16.h>
#include <stdint.h>

#define NV   65536   // active voxels
#define KOFF 27      // kernel offsets
#define CIN  128
#define COUT 128
#define NSEC (NV + 128)   // nbr_t per-offset stride (16B-aligned, holds dummy slot)

typedef __bf16 bf16x8 __attribute__((ext_vector_type(8)));
typedef float  f32x4  __attribute__((ext_vector_type(4)));

__device__ __forceinline__ void async_copy16(void* lds, const void* g) {
    __builtin_amdgcn_global_load_lds(
        (const __attribute__((address_space(1))) void*)g,
        (__attribute__((address_space(3))) void*)lds,
        16, 0, 0);
}

// ---- fused prep kernel (identical to R4: 16x16 fragment-major B + ------
// thread-order-transposed rulebook) --------------------------------------
#define JOB_A_BLOCKS 4097
#define JOB_B_BLOCKS 216    // 27*4*4*2*64 chunks / 256
#define JOB_S_BLOCKS 1728   // 27*65536/4/256

__global__ void k_prep_all(const float* __restrict__ f,
                           uint4* __restrict__ fb4,
                           const float* __restrict__ w,
                           uint4* __restrict__ wfrag4,
                           const int4* __restrict__ in4,
                           const int4* __restrict__ out4,
                           int* __restrict__ nbr) {
    const int b = blockIdx.x;
    const int t = threadIdx.x;
    if (b < JOB_A_BLOCKS) {
        int i = b * 256 + t;
        int total8  = (NV + 1) * CIN / 8;
        int nvalid8 = NV * CIN / 8;
        if (i >= total8) return;
        union { uint4 u; __hip_bfloat16 h[8]; } p;
        if (i < nvalid8) {
            const float4* f4 = (const float4*)f;
            float4 a = f4[i * 2];
            float4 c = f4[i * 2 + 1];
            p.h[0] = __float2bfloat16(a.x);
            p.h[1] = __float2bfloat16(a.y);
            p.h[2] = __float2bfloat16(a.z);
            p.h[3] = __float2bfloat16(a.w);
            p.h[4] = __float2bfloat16(c.x);
            p.h[5] = __float2bfloat16(c.y);
            p.h[6] = __float2bfloat16(c.z);
            p.h[7] = __float2bfloat16(c.w);
        } else {
            p.u = make_uint4(0, 0, 0, 0);
        }
        fb4[i] = p.u;
    } else if (b < JOB_A_BLOCKS + JOB_B_BLOCKS) {
        int c    = (b - JOB_A_BLOCKS) * 256 + t;
        int lane = c & 63;
        int nt   = (c >> 6) & 1;
        int ks   = (c >> 7) & 3;
        int wv   = (c >> 9) & 3;
        int k    = c >> 11;
        int cout = wv * 32 + nt * 16 + (lane & 15);
        int cin0 = ks * 32 + (lane >> 4) * 8;
        const float* wk = w + k * 16384;
        union { uint4 u; __hip_bfloat16 h[8]; } p;
        #pragma unroll
        for (int j = 0; j < 8; ++j)
            p.h[j] = __float2bfloat16(wk[(cin0 + j) * 128 + cout]);
        wfrag4[c] = p.u;
    } else {
        int i = (b - JOB_A_BLOCKS - JOB_B_BLOCKS) * 256 + t;
        int k = i >> 14;
        int4 ii = in4[i];
        int4 oo = out4[i];
        int* nb = nbr + (size_t)k * NSEC;
        auto POS = [](int o) {
            return (o >> 7) * 128 + (o & 15) * 8 + ((o >> 4) & 7);
        };
        nb[POS(oo.x)] = ii.x;
        nb[POS(oo.y)] = ii.y;
        nb[POS(oo.z)] = ii.z;
        nb[POS(oo.w)] = ii.w;
    }
}

// ---- main gather-GEMM kernel -------------------------------------------
// PERSISTENT 2-TILE blocks: 256 blocks (1/CU), each owns tiles 2p, 2p+1.
// B(k) is loaded ONCE per k and feeds BOTH tiles' MFMAs -> per-CU B L2
// traffic halves (64 -> 32 KB/offset), the last redundant VMEM stream in
// R4 (the fitted bottleneck: per-CU L2/TA service). Everything else is
// R4-identical: wave = 128 rows x 32 cols, disjoint B slices, XOR-map
// staging, transposed-nbr int4 loads, counted vmcnt, 1 barrier per phase.
// Phase sequence: ... [stage(T1,k) | compute(T0,k)] [stage(T0,k+1)+B(k+1)
// | compute(T1,k)] ...  acc0/acc1 statically named (no runtime indexing).
__global__ __launch_bounds__(256, 2)
void sp_conv_main(const __hip_bfloat16* __restrict__ feats,
                  const uint4* __restrict__ wfrag,
                  const int* __restrict__ nbrt,
                  const float* __restrict__ bias,
                  float* __restrict__ out) {
    __shared__ unsigned char smem[65536];   // two 32 KB A buffers

    const int t   = threadIdx.x;
    const int bid = blockIdx.x;             // 256 blocks
    // XCD swizzle on the PAIR index: XCD x owns pairs [x*32, x*32+32)
    // -> tiles [x*64, x*64+64), same locality footprint as R4.
    const int p    = (bid & 7) * 32 + (bid >> 3);
    const int t0A  = (p * 2) * 128;         // tile T0 row base
    const int t0B  = (p * 2 + 1) * 128;     // tile T1 row base

    const int w    = t >> 6;
    const int lane = t & 63;
    const int lr   = lane & 15;
    const int quad = lane >> 4;

    // staging map (R4): LDS slot (row=i*16+srow, phys chunk t&15) holds
    // global chunk (t&15)^(row&15) -> conflict-free ds_read_b128
    const int srow  = t >> 4;
    const int sbyte = ((t & 15) ^ srow) * 16;

    f32x4 acc0[8][2] = {};   // T0 accumulator (64 regs, AGPR-eligible)
    f32x4 acc1[8][2] = {};   // T1 accumulator
    uint4 bA[4][2], bB[4][2];
    int arows[8];

    const unsigned char* featsB = (const unsigned char*)feats;

    auto NLOAD = [&](int k, int tbase) {   // 2 x int4: rows i*16+srow
        const int4* np = (const int4*)(nbrt + (size_t)k * NSEC + tbase + srow * 8);
        int4 a0 = np[0];
        int4 a1 = np[1];
        arows[0] = a0.x; arows[1] = a0.y; arows[2] = a0.z; arows[3] = a0.w;
        arows[4] = a1.x; arows[5] = a1.y; arows[6] = a1.z; arows[7] = a1.w;
    };
    auto STAGE = [&](int sb) {
        #pragma unroll
        for (int i = 0; i < 8; ++i) {
            unsigned ar = min((unsigned)arows[i], (unsigned)NV);
            async_copy16(smem + sb + i * 4096 + t * 16,
                         featsB + (size_t)ar * 256 + sbyte);
        }
    };
    auto BLOAD = [&](const uint4* wfk, uint4 (&b)[4][2]) {
        #pragma unroll
        for (int ks = 0; ks < 4; ++ks)
            #pragma unroll
            for (int nt = 0; nt < 2; ++nt)
                b[ks][nt] = wfk[ks * 128 + nt * 64];
    };
    auto COMPUTE = [&](int rb, uint4 (&buse)[4][2], f32x4 (&ac)[8][2]) {
        #pragma unroll
        for (int ks = 0; ks < 4; ++ks) {
            bf16x8 af[8];
            #pragma unroll
            for (int mt = 0; mt < 8; ++mt)
                af[mt] = *(const bf16x8*)(smem + rb + (mt * 16 + lr) * 256 +
                                          (((ks * 4 + quad) ^ lr) * 16));
            #pragma unroll
            for (int mt = 0; mt < 8; ++mt)
                #pragma unroll
                for (int nt = 0; nt < 2; ++nt)
                    ac[mt][nt] = __builtin_amdgcn_mfma_f32_16x16x32_bf16(
                        af[mt], *(const bf16x8*)&buse[ks][nt],
                        ac[mt][nt], 0, 0, 0);
        }
    };

    // phase A(k): stage (T1,k)->buf1, nload (k+1,T0), compute T0@k from buf0
    auto PHA = [&](int k, uint4 (&buse)[4][2]) {
        STAGE(32768);
        __builtin_amdgcn_sched_barrier(0);     // staging oldest in vm queue
        NLOAD(min(k + 1, KOFF - 1), t0A);
        COMPUTE(0, buse, acc0);
        __builtin_amdgcn_sched_barrier(0);
        asm volatile("s_waitcnt vmcnt(2)" ::: "memory");   // stage done
        __builtin_amdgcn_s_barrier();
        __builtin_amdgcn_sched_barrier(0);
    };
    // phase B(k): stage (T0,k+1)->buf0, nload (k+1,T1), bload B(k+1),
    //             compute T1@k from buf1
    auto PHB = [&](int k, uint4 (&buse)[4][2], uint4 (&bload)[4][2]) {
        STAGE(0);
        __builtin_amdgcn_sched_barrier(0);
        NLOAD(min(k + 1, KOFF - 1), t0B);
        BLOAD(wfrag + (k + 1) * 2048 + w * 512 + lane, bload);
        COMPUTE(32768, buse, acc1);
        __builtin_amdgcn_sched_barrier(0);
        asm volatile("s_waitcnt vmcnt(10)" ::: "memory");  // stage done; nbr+B fly
        __builtin_amdgcn_s_barrier();
        __builtin_amdgcn_sched_barrier(0);
    };

    // ---- prologue: nbr(T0,0) -> stage buf0 -> nbr(T1,0) + B(0) ----
    NLOAD(0, t0A);
    STAGE(0);
    __builtin_amdgcn_sched_barrier(0);
    NLOAD(0, t0B);
    BLOAD(wfrag + w * 512 + lane, bA);
    asm volatile("s_waitcnt vmcnt(10)" ::: "memory");
    __builtin_amdgcn_s_barrier();
    __builtin_amdgcn_sched_barrier(0);

    // ---- k-loop, unrolled x2 for static bA/bB roles (k=0..25) ----
    #pragma unroll 1
    for (int kk = 0; kk < KOFF - 1; kk += 2) {
        PHA(kk,     bA);         // even k: consume bA
        PHB(kk,     bA, bB);     //   ... and prefetch bB = B(k+1)
        PHA(kk + 1, bB);         // odd k: consume bB
        PHB(kk + 1, bB, bA);     //   ... and prefetch bA = B(k+2)
    }

    // ---- tail k=26 (bA = B(26) from PHB(25)) ----
    STAGE(32768);                              // (T1,26) -> buf1
    __builtin_amdgcn_sched_barrier(0);
    COMPUTE(0, bA, acc0);                      // T0@26 from buf0
    asm volatile("s_waitcnt vmcnt(0)" ::: "memory");
    __builtin_amdgcn_s_barrier();
    COMPUTE(32768, bA, acc1);                  // T1@26 from buf1

    // ---- epilogue: C/D layout col = lane&15, row = quad*4 + reg ----
    const int n0w = w * 32;
    float bv[2];
    #pragma unroll
    for (int nt = 0; nt < 2; ++nt) bv[nt] = bias[n0w + nt * 16 + lr];

    #pragma unroll
    for (int mt = 0; mt < 8; ++mt) {
        #pragma unroll
        for (int nt = 0; nt < 2; ++nt) {
            #pragma unroll
            for (int r = 0; r < 4; ++r) {
                int rr = mt * 16 + quad * 4 + r;
                int cc = n0w + nt * 16 + lr;
                out[(size_t)(t0A + rr) * COUT + cc] = acc0[mt][nt][r] + bv[nt];
                out[(size_t)(t0B + rr) * COUT + cc] = acc1[mt][nt][r] + bv[nt];
            }
        }
    }
}

// ---- launch -------------------------------------------------------------

extern "C" void kernel_launch(void* const* d_in, const int* in_sizes, int n_in,
                              void* d_out, int out_size, void* d_ws, size_t ws_size,
                              hipStream_t stream) {
    const float* features = (const float*)d_in[0];   // [N,128] f32
    const float* weight   = (const float*)d_in[1];   // [27,128,128] f32
    const float* bias     = (const float*)d_in[2];   // [128] f32
    const int*   in_idx   = (const int*)d_in[3];     // [27,N] i32
    const int*   out_idx  = (const int*)d_in[4];     // [27,N] i32
    float* out = (float*)d_out;                      // [N,128] f32

    uint8_t* ws = (uint8_t*)d_ws;
    size_t off = 0;
    __hip_bfloat16* feats_bf = (__hip_bfloat16*)(ws + off);       // (N+1)*256 B
    off += (size_t)(NV + 1) * CIN * 2;
    off = (off + 255) & ~(size_t)255;
    uint4* wfrag = (uint4*)(ws + off);                            // 27*2048*16 B
    off += (size_t)KOFF * CIN * COUT * 2;
    off = (off + 255) & ~(size_t)255;
    int* nbr = (int*)(ws + off);                                  // 27*NSEC*4 (transposed)

    // init nbr_t to 0xFFFFFFFF (-1 = "no neighbor"; main clamps to zero row)
    hipMemsetAsync(nbr, 0xFF, (size_t)KOFF * NSEC * 4, stream);

    // fused prep: feature cast + weight fragment-permute + rulebook scatter
    k_prep_all<<<JOB_A_BLOCKS + JOB_B_BLOCKS + JOB_S_BLOCKS, 256, 0, stream>>>(
        features, (uint4*)feats_bf, weight, wfrag,
        (const int4*)in_idx, (const int4*)out_idx, nbr);

    // main gather-GEMM: 256 persistent blocks x 2 tiles of 128 rows
    sp_conv_main<<<256, 256, 0, stream>>>(feats_bf, wfrag, nbr, bias, out);
}

// Round 10
// 152.928 us; speedup vs baseline: 1.1288x; 1.1288x over previous
//
#include <hip/hip_runtime.h>
#include <hip/hip_bf16.h>
#include <stdint.h>

#define NV   65536   // active voxels
#define KOFF 27      // kernel offsets
#define CIN  128
#define COUT 128
#define NSEC (NV + 128)   // nbr_t per-offset stride (16B-aligned, holds dummy slot)

typedef __bf16 bf16x8 __attribute__((ext_vector_type(8)));
typedef float  f32x4  __attribute__((ext_vector_type(4)));

__device__ __forceinline__ void async_copy16(void* lds, const void* g) {
    __builtin_amdgcn_global_load_lds(
        (const __attribute__((address_space(1))) void*)g,
        (__attribute__((address_space(3))) void*)lds,
        16, 0, 0);
}

// ---- fused prep kernel (identical to R4) --------------------------------
#define JOB_A_BLOCKS 4097
#define JOB_B_BLOCKS 216    // 27*4*4*2*64 chunks / 256
#define JOB_S_BLOCKS 1728   // 27*65536/4/256

__global__ void k_prep_all(const float* __restrict__ f,
                           uint4* __restrict__ fb4,
                           const float* __restrict__ w,
                           uint4* __restrict__ wfrag4,
                           const int4* __restrict__ in4,
                           const int4* __restrict__ out4,
                           int* __restrict__ nbr) {
    const int b = blockIdx.x;
    const int t = threadIdx.x;
    if (b < JOB_A_BLOCKS) {
        int i = b * 256 + t;
        int total8  = (NV + 1) * CIN / 8;
        int nvalid8 = NV * CIN / 8;
        if (i >= total8) return;
        union { uint4 u; __hip_bfloat16 h[8]; } p;
        if (i < nvalid8) {
            const float4* f4 = (const float4*)f;
            float4 a = f4[i * 2];
            float4 c = f4[i * 2 + 1];
            p.h[0] = __float2bfloat16(a.x);
            p.h[1] = __float2bfloat16(a.y);
            p.h[2] = __float2bfloat16(a.z);
            p.h[3] = __float2bfloat16(a.w);
            p.h[4] = __float2bfloat16(c.x);
            p.h[5] = __float2bfloat16(c.y);
            p.h[6] = __float2bfloat16(c.z);
            p.h[7] = __float2bfloat16(c.w);
        } else {
            p.u = make_uint4(0, 0, 0, 0);
        }
        fb4[i] = p.u;
    } else if (b < JOB_A_BLOCKS + JOB_B_BLOCKS) {
        int c    = (b - JOB_A_BLOCKS) * 256 + t;
        int lane = c & 63;
        int nt   = (c >> 6) & 1;
        int ks   = (c >> 7) & 3;
        int wv   = (c >> 9) & 3;
        int k    = c >> 11;
        int cout = wv * 32 + nt * 16 + (lane & 15);
        int cin0 = ks * 32 + (lane >> 4) * 8;
        const float* wk = w + k * 16384;
        union { uint4 u; __hip_bfloat16 h[8]; } p;
        #pragma unroll
        for (int j = 0; j < 8; ++j)
            p.h[j] = __float2bfloat16(wk[(cin0 + j) * 128 + cout]);
        wfrag4[c] = p.u;
    } else {
        int i = (b - JOB_A_BLOCKS - JOB_B_BLOCKS) * 256 + t;
        int k = i >> 14;
        int4 ii = in4[i];
        int4 oo = out4[i];
        int* nb = nbr + (size_t)k * NSEC;
        auto POS = [](int o) {
            return (o >> 7) * 128 + (o & 15) * 8 + ((o >> 4) & 7);
        };
        nb[POS(oo.x)] = ii.x;
        nb[POS(oo.y)] = ii.y;
        nb[POS(oo.z)] = ii.z;
        nb[POS(oo.w)] = ii.w;
    }
}

// ---- main gather-GEMM kernel -------------------------------------------
// R5 geometry, DE-PINNED: wave grid 2x2, each wave 64 rows x 64 cols.
// Two-pipe model (fits R0-R9): T = LDS/85 + L2/60 per CU per offset;
// r=64 gives 1542+2184=3726 vs R4's 3084+1092=4176 cyc. R5 tested this
// geometry with 6 mid-loop sched_barrier pins (m141 anti-pattern) and R2
// with register spill; this is the first clean test: in-place bcur rotate
// (64 B-regs, no spill) + R4's exact 3-pin placement (after STAGE, before
// vmcnt, after barrier) and nothing else pinned.
__global__ __launch_bounds__(256, 2)
void sp_conv_main(const __hip_bfloat16* __restrict__ feats,
                  const uint4* __restrict__ wfrag,
                  const int* __restrict__ nbrt,
                  const float* __restrict__ bias,
                  float* __restrict__ out) {
    __shared__ unsigned char smem[65536];   // two 32 KB A buffers

    const int t   = threadIdx.x;
    const int bid = blockIdx.x;
    // XCD swizzle: consecutive 64-tile ranges per XCD (512 % 8 == 0)
    const int tile0 = ((bid & 7) * 64 + (bid >> 3)) * 128;

    const int w    = t >> 6;
    const int lane = t & 63;
    const int lr   = lane & 15;
    const int quad = lane >> 4;
    const int wr   = w >> 1;     // wave row: rows [wr*64, wr*64+64)
    const int wc   = w & 1;      // wave col: cols [wc*64, wc*64+64)

    // staging map (R4): LDS slot (row=i*16+srow, phys chunk t&15) holds
    // global chunk (t&15)^(row&15) -> conflict-free ds_read_b128
    const int srow  = t >> 4;
    const int sbyte = ((t & 15) ^ srow) * 16;

    f32x4 acc[4][4] = {};   // 64 VGPRs
    uint4 bcur[4][4];       // 64 VGPRs, rotated in place (WAR-ordered)
    int   arows[8];

    const unsigned char* featsB = (const unsigned char*)feats;

    auto NLOAD = [&](int k) {   // 2 x int4 (transposed rulebook, R4-proven)
        const int4* np = (const int4*)(nbrt + (size_t)k * NSEC + tile0 + srow * 8);
        int4 a0 = np[0];
        int4 a1 = np[1];
        arows[0] = a0.x; arows[1] = a0.y; arows[2] = a0.z; arows[3] = a0.w;
        arows[4] = a1.x; arows[5] = a1.y; arows[6] = a1.z; arows[7] = a1.w;
    };
    auto STAGE = [&](int sb) {
        #pragma unroll
        for (int i = 0; i < 8; ++i) {
            unsigned ar = min((unsigned)arows[i], (unsigned)NV);
            async_copy16(smem + sb + i * 4096 + t * 16,
                         featsB + (size_t)ar * 256 + sbyte);
        }
    };
    // B frag (ks,nt'): chunk = k*2048 + wc*1024 + (nt'>>1)*512 + ks*128 + (nt'&1)*64 + lane
    auto BLOAD2 = [&](const uint4* wfk, int ks0) {   // fills bcur[ks0..ks0+1]
        #pragma unroll
        for (int ks = 0; ks < 2; ++ks)
            #pragma unroll
            for (int nt = 0; nt < 4; ++nt)
                bcur[ks0 + ks][nt] =
                    wfk[(nt >> 1) * 512 + (nt & 1) * 64 + (ks0 + ks) * 128];
    };
    auto AFLOAD = [&](int rb, int ks, bf16x8 (&af)[4]) {
        #pragma unroll
        for (int mt = 0; mt < 4; ++mt)
            af[mt] = *(const bf16x8*)(smem + rb + (wr * 64 + mt * 16 + lr) * 256 +
                                      (((ks * 4 + quad) ^ lr) * 16));
    };
    auto MFMA16 = [&](bf16x8 (&af)[4], uint4 (&b)[4]) {
        #pragma unroll
        for (int mt = 0; mt < 4; ++mt)
            #pragma unroll
            for (int nt = 0; nt < 4; ++nt)
                acc[mt][nt] = __builtin_amdgcn_mfma_f32_16x16x32_bf16(
                    af[mt], *(const bf16x8*)&b[nt], acc[mt][nt], 0, 0, 0);
    };

    // ---- prologue ----
    NLOAD(0);
    STAGE(0);
    __builtin_amdgcn_sched_barrier(0);   // staging ops oldest in vm queue
    NLOAD(1);
    {
        const uint4* wf0 = wfrag + wc * 1024 + lane;
        BLOAD2(wf0, 0);
        BLOAD2(wf0, 2);
    }
    asm volatile("s_waitcnt vmcnt(18)" ::: "memory");   // 2 nbr + 16 B younger
    __builtin_amdgcn_s_barrier();
    __builtin_amdgcn_sched_barrier(0);

    // ---- one offset (no mid-loop pins; WAR orders the in-place refill) ----
    auto ITER = [&](int k, int rb) {
        const uint4* wfn = wfrag + (k + 1) * 2048 + wc * 1024 + lane;
        STAGE(rb ^ 32768);
        __builtin_amdgcn_sched_barrier(0);     // keep staging oldest (R4 pin)
        NLOAD(min(k + 2, KOFF - 1));
        {
            bf16x8 af[4];
            AFLOAD(rb, 0, af);
            MFMA16(af, bcur[0]);
            AFLOAD(rb, 1, af);
            MFMA16(af, bcur[1]);
        }
        BLOAD2(wfn, 0);                        // refill slots 0-1 (k+1)
        {
            bf16x8 af[4];
            AFLOAD(rb, 2, af);
            MFMA16(af, bcur[2]);
            AFLOAD(rb, 3, af);
            MFMA16(af, bcur[3]);
        }
        BLOAD2(wfn, 2);                        // refill slots 2-3 (k+1)
        __builtin_amdgcn_sched_barrier(0);     // (R4 pin)
        asm volatile("s_waitcnt vmcnt(18)" ::: "memory");  // staging done
        __builtin_amdgcn_s_barrier();
        __builtin_amdgcn_sched_barrier(0);     // (R4 pin)
    };

    #pragma unroll 1
    for (int kk = 0; kk < KOFF - 1; kk += 2) {
        ITER(kk,     0);       // even k: read buf0, stage buf1
        ITER(kk + 1, 32768);   // odd  k: read buf1, stage buf0
    }

    // ---- tail k=26: buf0; bcur holds B(26); no loads/barriers ----
    #pragma unroll
    for (int ks = 0; ks < 4; ++ks) {
        bf16x8 af[4];
        AFLOAD(0, ks, af);
        MFMA16(af, bcur[ks]);
    }

    // ---- epilogue: C/D layout col = lane&15, row = quad*4 + reg ----
    const int n0w = wc * 64;
    float bv[4];
    #pragma unroll
    for (int nt = 0; nt < 4; ++nt) bv[nt] = bias[n0w + nt * 16 + lr];

    #pragma unroll
    for (int mt = 0; mt < 4; ++mt) {
        #pragma unroll
        for (int nt = 0; nt < 4; ++nt) {
            #pragma unroll
            for (int r = 0; r < 4; ++r) {
                int grow = tile0 + wr * 64 + mt * 16 + quad * 4 + r;
                out[(size_t)grow * COUT + n0w + nt * 16 + lr] =
                    acc[mt][nt][r] + bv[nt];
            }
        }
    }
}

// ---- launch -------------------------------------------------------------

extern "C" void kernel_launch(void* const* d_in, const int* in_sizes, int n_in,
                              void* d_out, int out_size, void* d_ws, size_t ws_size,
                              hipStream_t stream) {
    const float* features = (const float*)d_in[0];   // [N,128] f32
    const float* weight   = (const float*)d_in[1];   // [27,128,128] f32
    const float* bias     = (const float*)d_in[2];   // [128] f32
    const int*   in_idx   = (const int*)d_in[3];     // [27,N] i32
    const int*   out_idx  = (const int*)d_in[4];     // [27,N] i32
    float* out = (float*)d_out;                      // [N,128] f32

    uint8_t* ws = (uint8_t*)d_ws;
    size_t off = 0;
    __hip_bfloat16* feats_bf = (__hip_bfloat16*)(ws + off);       // (N+1)*256 B
    off += (size_t)(NV + 1) * CIN * 2;
    off = (off + 255) & ~(size_t)255;
    uint4* wfrag = (uint4*)(ws + off);                            // 27*2048*16 B
    off += (size_t)KOFF * CIN * COUT * 2;
    off = (off + 255) & ~(size_t)255;
    int* nbr = (int*)(ws + off);                                  // 27*NSEC*4 (transposed)

    // init nbr_t to 0xFFFFFFFF (-1 = "no neighbor"; main clamps to zero row)
    hipMemsetAsync(nbr, 0xFF, (size_t)KOFF * NSEC * 4, stream);

    // fused prep: feature cast + weight fragment-permute + rulebook scatter
    k_prep_all<<<JOB_A_BLOCKS + JOB_B_BLOCKS + JOB_S_BLOCKS, 256, 0, stream>>>(
        features, (uint4*)feats_bf, weight, wfrag,
        (const int4*)in_idx, (const int4*)out_idx, nbr);

    // main gather-GEMM: 512 tiles of 128 rows
    sp_conv_main<<<NV / 128, 256, 0, stream>>>(feats_bf, wfrag, nbr, bias, out);
}

// Round 11
// 149.135 us; speedup vs baseline: 1.1575x; 1.0254x over previous
//
#include <hip/hip_runtime.h>
#include <hip/hip_bf16.h>
#include <stdint.h>

#define NV   65536   // active voxels
#define KOFF 27      // kernel offsets
#define CIN  128
#define COUT 128
#define NSEC (NV + 128)   // nbr_t per-offset stride (16B-aligned, holds dummy slot)

typedef __bf16 bf16x8 __attribute__((ext_vector_type(8)));
typedef float  f32x4  __attribute__((ext_vector_type(4)));

__device__ __forceinline__ void async_copy16(void* lds, const void* g) {
    __builtin_amdgcn_global_load_lds(
        (const __attribute__((address_space(1))) void*)g,
        (__attribute__((address_space(3))) void*)lds,
        16, 0, 0);
}

// ---- fused prep kernel --------------------------------------------------
// Job S fix (R10 post-mortem): ~1.07M padded pairs all carry out_idx = N,
// and the old code stored every one of them to the SAME dummy slot ->
// million-way same-address store serialization across 256 CUs (Guideline
// 12 pathology). The sentinel is already provided by the memset and the
// dummy slot is never read -> GUARD THE STORE OUT entirely.
#define JOB_A_BLOCKS 4097
#define JOB_B_BLOCKS 216    // 27*4*4*2*64 chunks / 256
#define JOB_S_BLOCKS 1728   // 27*65536/4/256

__global__ void k_prep_all(const float* __restrict__ f,
                           uint4* __restrict__ fb4,
                           const float* __restrict__ w,
                           uint4* __restrict__ wfrag4,
                           const int4* __restrict__ in4,
                           const int4* __restrict__ out4,
                           int* __restrict__ nbr) {
    const int b = blockIdx.x;
    const int t = threadIdx.x;
    if (b < JOB_A_BLOCKS) {
        int i = b * 256 + t;
        int total8  = (NV + 1) * CIN / 8;
        int nvalid8 = NV * CIN / 8;
        if (i >= total8) return;
        union { uint4 u; __hip_bfloat16 h[8]; } p;
        if (i < nvalid8) {
            const float4* f4 = (const float4*)f;
            float4 a = f4[i * 2];
            float4 c = f4[i * 2 + 1];
            p.h[0] = __float2bfloat16(a.x);
            p.h[1] = __float2bfloat16(a.y);
            p.h[2] = __float2bfloat16(a.z);
            p.h[3] = __float2bfloat16(a.w);
            p.h[4] = __float2bfloat16(c.x);
            p.h[5] = __float2bfloat16(c.y);
            p.h[6] = __float2bfloat16(c.z);
            p.h[7] = __float2bfloat16(c.w);
        } else {
            p.u = make_uint4(0, 0, 0, 0);
        }
        fb4[i] = p.u;
    } else if (b < JOB_A_BLOCKS + JOB_B_BLOCKS) {
        int c    = (b - JOB_A_BLOCKS) * 256 + t;
        int lane = c & 63;
        int nt   = (c >> 6) & 1;
        int ks   = (c >> 7) & 3;
        int wv   = (c >> 9) & 3;
        int k    = c >> 11;
        int cout = wv * 32 + nt * 16 + (lane & 15);
        int cin0 = ks * 32 + (lane >> 4) * 8;
        const float* wk = w + k * 16384;
        union { uint4 u; __hip_bfloat16 h[8]; } p;
        #pragma unroll
        for (int j = 0; j < 8; ++j)
            p.h[j] = __float2bfloat16(wk[(cin0 + j) * 128 + cout]);
        wfrag4[c] = p.u;
    } else {
        int i = (b - JOB_A_BLOCKS - JOB_B_BLOCKS) * 256 + t;
        int k = i >> 14;
        int4 ii = in4[i];
        int4 oo = out4[i];
        int* nb = nbr + (size_t)k * NSEC;
        auto POS = [](int o) {
            return (o >> 7) * 128 + (o & 15) * 8 + ((o >> 4) & 7);
        };
        // transposed scatter, VALID PAIRS ONLY (padding -> no store)
        if ((unsigned)oo.x < NV) nb[POS(oo.x)] = ii.x;
        if ((unsigned)oo.y < NV) nb[POS(oo.y)] = ii.y;
        if ((unsigned)oo.z < NV) nb[POS(oo.z)] = ii.z;
        if ((unsigned)oo.w < NV) nb[POS(oo.w)] = ii.w;
    }
}

// ---- main gather-GEMM kernel (R4, byte-identical: proven 57.0 µs) -------
// BM=128, 2 blocks/CU, wave = 128 rows x 32 cols, LDS double-buffer,
// transposed-nbr int4 loads, counted vmcnt(10), 1 barrier per offset.
__global__ __launch_bounds__(256, 2)
void sp_conv_main(const __hip_bfloat16* __restrict__ feats,
                  const uint4* __restrict__ wfrag,
                  const int* __restrict__ nbrt,
                  const float* __restrict__ bias,
                  float* __restrict__ out) {
    __shared__ unsigned char smem[65536];   // two 32 KB A buffers

    const int t   = threadIdx.x;
    const int bid = blockIdx.x;
    // XCD swizzle: consecutive 64-tile ranges per XCD (512 % 8 == 0, bijective)
    const int tile0 = ((bid & 7) * 64 + (bid >> 3)) * 128;

    const int w    = t >> 6;
    const int lane = t & 63;
    const int lr   = lane & 15;
    const int quad = lane >> 4;

    // staging-side XOR map: LDS slot (row = i*16 + srow, physchunk = t&15)
    // holds global 16B chunk (t&15) ^ (row&15) -> conflict-free ds_read_b128
    const int srow  = t >> 4;
    const int sbyte = ((t & 15) ^ srow) * 16;

    f32x4 acc[8][2] = {};  // 64 VGPRs

    const unsigned char* featsB = (const unsigned char*)feats;

    int  arows[8];
    uint4 bA[4][2], bB[4][2];   // [ks][nt] fragment regs (role-swapped)

    auto NLOAD = [&](int k) {   // 2 x int4: rows i*16+srow, i=0..7
        const int4* np = (const int4*)(nbrt + (size_t)k * NSEC + tile0 + srow * 8);
        int4 a0 = np[0];
        int4 a1 = np[1];
        arows[0] = a0.x; arows[1] = a0.y; arows[2] = a0.z; arows[3] = a0.w;
        arows[4] = a1.x; arows[5] = a1.y; arows[6] = a1.z; arows[7] = a1.w;
    };
    auto STAGE = [&](int sb) {
        #pragma unroll
        for (int i = 0; i < 8; ++i) {
            unsigned ar = min((unsigned)arows[i], (unsigned)NV);
            async_copy16(smem + sb + i * 4096 + t * 16,
                         featsB + (size_t)ar * 256 + sbyte);
        }
    };
    auto BLOAD = [&](const uint4* wfk, uint4 (&b)[4][2]) {
        #pragma unroll
        for (int ks = 0; ks < 4; ++ks)
            #pragma unroll
            for (int nt = 0; nt < 2; ++nt)
                b[ks][nt] = wfk[ks * 128 + nt * 64];
    };
    auto AFLOAD = [&](int rb, int ks, bf16x8 (&af)[8]) {
        #pragma unroll
        for (int mt = 0; mt < 8; ++mt)
            af[mt] = *(const bf16x8*)(smem + rb + (mt * 16 + lr) * 256 +
                                      (((ks * 4 + quad) ^ lr) * 16));
    };
    auto MFMA16 = [&](bf16x8 (&af)[8], uint4 (&b)[2]) {
        #pragma unroll
        for (int mt = 0; mt < 8; ++mt)
            #pragma unroll
            for (int nt = 0; nt < 2; ++nt)
                acc[mt][nt] = __builtin_amdgcn_mfma_f32_16x16x32_bf16(
                    af[mt], *(const bf16x8*)&b[nt], acc[mt][nt], 0, 0, 0);
    };

    // ---- prologue: nbr(0) -> stage A0 -> prefetch nbr(1), B(0) ----
    NLOAD(0);
    STAGE(0);
    __builtin_amdgcn_sched_barrier(0);   // staging ops oldest in vm queue
    NLOAD(1);
    BLOAD(wfrag + w * 512 + lane, bA);
    // 10 younger vm ops (2 nbr + 8 B) -> staging A0 guaranteed complete
    asm volatile("s_waitcnt vmcnt(10)" ::: "memory");
    __builtin_amdgcn_s_barrier();
    __builtin_amdgcn_sched_barrier(0);

    // ---- one offset; buse consumed, bload prefilled for k+1 ----
    auto ITER = [&](int k, int rb, uint4 (&buse)[4][2], uint4 (&bload)[4][2]) {
        // issue A(k+1) staging first (oldest), then nbr(k+2) + B(k+1)
        STAGE(rb ^ 32768);
        __builtin_amdgcn_sched_barrier(0);
        NLOAD(min(k + 2, KOFF - 1));   // dup at k=25 harmless
        BLOAD(wfrag + (k + 1) * 2048 + w * 512 + lane, bload);
        // compute on buf rb with buse (no VMEM ops in here)
        #pragma unroll
        for (int ks = 0; ks < 4; ++ks) {
            bf16x8 af[8];
            AFLOAD(rb, ks, af);
            __builtin_amdgcn_s_setprio(1);
            MFMA16(af, buse[ks]);
            __builtin_amdgcn_s_setprio(0);
        }
        __builtin_amdgcn_sched_barrier(0);
        // own 8 staging loads complete; 10 nbr/B stay in flight (T4)
        asm volatile("s_waitcnt vmcnt(10)" ::: "memory");
        __builtin_amdgcn_s_barrier();
        __builtin_amdgcn_sched_barrier(0);
    };

    #pragma unroll 1
    for (int kk = 0; kk < KOFF - 1; kk += 2) {
        ITER(kk,     0,     bA, bB);   // even k: read buf0, stage buf1
        ITER(kk + 1, 32768, bB, bA);   // odd  k: read buf1, stage buf0
    }

    // ---- tail k=26: read buf0 with bA; no staging, no barriers ----
    #pragma unroll
    for (int ks = 0; ks < 4; ++ks) {
        bf16x8 af[8];
        AFLOAD(0, ks, af);
        MFMA16(af, bA[ks]);
    }

    // ---- epilogue: C/D layout col = lane&15, row = quad*4 + reg ----
    const int n0w = w * 32;
    float bv[2];
    #pragma unroll
    for (int nt = 0; nt < 2; ++nt) bv[nt] = bias[n0w + nt * 16 + lr];

    #pragma unroll
    for (int mt = 0; mt < 8; ++mt) {
        #pragma unroll
        for (int nt = 0; nt < 2; ++nt) {
            #pragma unroll
            for (int r = 0; r < 4; ++r) {
                int grow = tile0 + mt * 16 + quad * 4 + r;
                out[(size_t)grow * COUT + n0w + nt * 16 + lr] =
                    acc[mt][nt][r] + bv[nt];
            }
        }
    }
}

// ---- launch -------------------------------------------------------------

extern "C" void kernel_launch(void* const* d_in, const int* in_sizes, int n_in,
                              void* d_out, int out_size, void* d_ws, size_t ws_size,
                              hipStream_t stream) {
    const float* features = (const float*)d_in[0];   // [N,128] f32
    const float* weight   = (const float*)d_in[1];   // [27,128,128] f32
    const float* bias     = (const float*)d_in[2];   // [128] f32
    const int*   in_idx   = (const int*)d_in[3];     // [27,N] i32
    const int*   out_idx  = (const int*)d_in[4];     // [27,N] i32
    float* out = (float*)d_out;                      // [N,128] f32

    uint8_t* ws = (uint8_t*)d_ws;
    size_t off = 0;
    __hip_bfloat16* feats_bf = (__hip_bfloat16*)(ws + off);       // (N+1)*256 B
    off += (size_t)(NV + 1) * CIN * 2;
    off = (off + 255) & ~(size_t)255;
    uint4* wfrag = (uint4*)(ws + off);                            // 27*2048*16 B
    off += (size_t)KOFF * CIN * COUT * 2;
    off = (off + 255) & ~(size_t)255;
    int* nbr = (int*)(ws + off);                                  // 27*NSEC*4 (transposed)

    // init nbr_t to 0xFFFFFFFF (-1 = "no neighbor"; main clamps to zero row)
    hipMemsetAsync(nbr, 0xFF, (size_t)KOFF * NSEC * 4, stream);

    // fused prep: feature cast + weight fragment-permute + rulebook scatter
    k_prep_all<<<JOB_A_BLOCKS + JOB_B_BLOCKS + JOB_S_BLOCKS, 256, 0, stream>>>(
        features, (uint4*)feats_bf, weight, wfrag,
        (const int4*)in_idx, (const int4*)out_idx, nbr);

    // main gather-GEMM: 512 tiles of 128 rows
    sp_conv_main<<<NV / 128, 256, 0, stream>>>(feats_bf, wfrag, nbr, bias, out);
}